// Round 1
// baseline (245.768 us; speedup 1.0000x reference)
//
#include <hip/hip_runtime.h>

// MultiQueryAttention with kv_len == 1: softmax over a singleton axis is
// identically 1, so the output is independent of query/Wq/key/Wk.
//   V[b,d]      = value[b,:]·Wv[:,d] + bv[d]                      (8 x 64)
//   out_vec[b,j]= sum_c V[b, c&63] * Wo[c,j] + bo[j]              (8 x 1024)
//   out[b,s,:]  = out_vec[b,:]  for all s                         (8 x 4096 x 1024)

#define D_MODEL 1024
#define HEAD_DIM 64
#define B_SIZE 8
#define S_LEN 4096

// K1: one block per batch. 256 threads: d = t&63, k-part = t>>6 (4 x 256 k).
__global__ __launch_bounds__(256) void k_project_v(
    const float* __restrict__ value, const float* __restrict__ Wv,
    const float* __restrict__ bv, float* __restrict__ Vout) {
  int b = blockIdx.x;
  int t = threadIdx.x;
  int d = t & 63;
  int part = t >> 6;  // 0..3
  const float* vrow = value + b * D_MODEL;
  float acc = 0.f;
  int k0 = part * 256;
#pragma unroll 8
  for (int i = 0; i < 256; ++i) {
    int k = k0 + i;
    // Wv row read: 64 consecutive d per wave -> 256B coalesced; vrow[k] broadcast.
    acc += vrow[k] * Wv[k * HEAD_DIM + d];
  }
  __shared__ float red[4][64];
  red[part][d] = acc;
  __syncthreads();
  if (t < 64) {
    Vout[b * HEAD_DIM + t] =
        red[0][t] + red[1][t] + red[2][t] + red[3][t] + bv[t];
  }
}

// K2: grid = 8 batches x 32 j-chunks (32 j each). 256 threads:
// j = t&31, c-part = t>>5 (8 x 128 c). Wo reads coalesced in j.
__global__ __launch_bounds__(256) void k_out_vec(
    const float* __restrict__ Vin, const float* __restrict__ Wo,
    const float* __restrict__ bo, float* __restrict__ outv) {
  int b = blockIdx.x >> 5;
  int jc = blockIdx.x & 31;
  int jbase = jc * 32;
  int t = threadIdx.x;

  __shared__ float Vsh[64];
  if (t < 64) Vsh[t] = Vin[b * HEAD_DIM + t];
  __syncthreads();

  int j = jbase + (t & 31);
  int part = t >> 5;  // 0..7
  int c0 = part * 128;
  float acc = 0.f;
#pragma unroll 8
  for (int i = 0; i < 128; ++i) {
    int c = c0 + i;
    // Vsh[c&63]: same address across the 32 j-lanes -> LDS broadcast (free).
    acc += Vsh[c & 63] * Wo[c * D_MODEL + j];
  }
  __shared__ float red[8][33];  // +1 pad
  red[part][t & 31] = acc;
  __syncthreads();
  if (t < 32) {
    float s = bo[jbase + t];
#pragma unroll
    for (int p = 0; p < 8; ++p) s += red[p][t];
    outv[b * D_MODEL + jbase + t] = s;
  }
}

// K3: broadcast out_vec over S. grid = 8 batches x 128 row-groups.
// Each thread holds one float4 of out_vec in a register and stores it to
// 32 rows; each block iteration writes one contiguous 4KB row.
__global__ __launch_bounds__(256) void k_broadcast(
    const float4* __restrict__ vec4, float4* __restrict__ out4) {
  int b = blockIdx.x >> 7;
  int g = blockIdx.x & 127;
  int t = threadIdx.x;  // 0..255 float4 lanes cover D_MODEL
  float4 v = vec4[b * 256 + t];
  size_t base = (size_t)b * S_LEN * 256 + t;
#pragma unroll 4
  for (int s = g; s < S_LEN; s += 128) {
    out4[base + (size_t)s * 256] = v;
  }
}

extern "C" void kernel_launch(void* const* d_in, const int* in_sizes, int n_in,
                              void* d_out, int out_size, void* d_ws,
                              size_t ws_size, hipStream_t stream) {
  // setup_inputs order: query(0) key(1) value(2) Wq(3) bq(4) Wk(5) bk(6)
  //                     Wv(7) bv(8) Wo(9) bo(10)
  const float* value = (const float*)d_in[2];
  const float* Wv = (const float*)d_in[7];
  const float* bv = (const float*)d_in[8];
  const float* Wo = (const float*)d_in[9];
  const float* bo = (const float*)d_in[10];

  float* V = (float*)d_ws;                  // 8*64 floats
  float* outv = (float*)d_ws + 1024;        // 8*1024 floats, 16B-aligned

  k_project_v<<<B_SIZE, 256, 0, stream>>>(value, Wv, bv, V);
  k_out_vec<<<B_SIZE * 32, 256, 0, stream>>>(V, Wo, bo, outv);
  k_broadcast<<<B_SIZE * 128, 256, 0, stream>>>((const float4*)outv,
                                                (float4*)d_out);
}

// Round 3
// 243.618 us; speedup vs baseline: 1.0088x; 1.0088x over previous
//
#include <hip/hip_runtime.h>

// MultiQueryAttention with kv_len == 1: softmax over a singleton axis is
// identically 1, so the output is independent of query/Wq/key/Wk.
//   V[b,d]      = value[b,:]·Wv[:,d] + bv[d]                      (8 x 64)
//   out_vec[b,j]= sum_c V[b, c&63] * Wo[c,j] + bo[j]              (8 x 1024)
//   out[b,s,:]  = out_vec[b,:]  for all s                         (8 x 4096 x 1024)
//
// Structure: 2 kernels.
//  A) k_outvec: 128 blocks (8 b x 16 j-slices of 64). Each block redundantly
//     recomputes V[b] (Wv is 256 KB, L2-hot; redundancy costs ~32 MB of L2
//     reads ~= 1 us — cheaper than a third launch + serialization).
//  B) k_broadcast: pure write-BW kernel, nontemporal stores via a native
//     clang vector type (HIP float4 is a class — rejected by the builtin),
//     4 KB contiguous per block-iteration.

#define D_MODEL 1024
#define HEAD_DIM 64
#define B_SIZE 8
#define S_LEN 4096

typedef float vfloat4 __attribute__((ext_vector_type(4)));

__global__ __launch_bounds__(256) void k_outvec(
    const float* __restrict__ value, const float4* __restrict__ Wv4,
    const float4* __restrict__ bv4, const float* __restrict__ Wo,
    const float* __restrict__ bo, float* __restrict__ outv) {
  int b = blockIdx.x >> 4;   // 0..7
  int jc = blockIdx.x & 15;  // 0..15
  int jbase = jc * 64;
  int t = threadIdx.x;

  // --- V[b,:] = value[b,:]·Wv + bv ---
  __shared__ __align__(16) float Vsh[64];
  {
    int d4 = t & 15;  // float4 column (64 floats = 16 float4)
    int kp = t >> 4;  // 0..15, 64 k each
    const float* vrow = value + b * D_MODEL;
    float4 acc = make_float4(0.f, 0.f, 0.f, 0.f);
    int k0 = kp * 64;
#pragma unroll 8
    for (int i = 0; i < 64; ++i) {
      int k = k0 + i;
      float v = vrow[k];           // 16 lanes share address -> L1 broadcast
      float4 w = Wv4[k * 16 + d4]; // 16 consecutive float4 = 256B segment
      acc.x += v * w.x;
      acc.y += v * w.y;
      acc.z += v * w.z;
      acc.w += v * w.w;
    }
    __shared__ float4 red[16][16];
    red[kp][d4] = acc;
    __syncthreads();
    if (t < 16) {
      float4 s = bv4[t];
#pragma unroll
      for (int p = 0; p < 16; ++p) {
        float4 r = red[p][t];
        s.x += r.x;
        s.y += r.y;
        s.z += r.z;
        s.w += r.w;
      }
      ((float4*)Vsh)[t] = s;
    }
    __syncthreads();
  }

  // --- out_vec slice: j in [jbase, jbase+64) ---
  int j = t & 63;
  int part = t >> 6;  // 0..3, 256 c each (wave-uniform)
  float acc = 0.f;
  int c0 = part * 256;
#pragma unroll 8
  for (int i = 0; i < 256; ++i) {
    int c = c0 + i;
    // Vsh[c&63] is wave-uniform within the wave -> LDS broadcast.
    acc += Vsh[c & 63] * Wo[c * D_MODEL + jbase + j];
  }
  __shared__ float red2[4][64];
  red2[part][j] = acc;
  __syncthreads();
  if (t < 64) {
    outv[b * D_MODEL + jbase + t] =
        red2[0][t] + red2[1][t] + red2[2][t] + red2[3][t] + bo[jbase + t];
  }
}

// Pure write-BW broadcast. grid = 8 b x 128 row-groups. Each block-iteration
// writes one contiguous 4 KB row; nontemporal to keep L2 clean.
__global__ __launch_bounds__(256) void k_broadcast(
    const vfloat4* __restrict__ vec4, vfloat4* __restrict__ out4) {
  int b = blockIdx.x >> 7;
  int g = blockIdx.x & 127;
  int t = threadIdx.x;  // 256 vfloat4 lanes cover D_MODEL
  vfloat4 v = vec4[b * 256 + t];
  vfloat4* p = out4 + (size_t)b * S_LEN * 256 + (size_t)g * 256 + t;
#pragma unroll 8
  for (int i = 0; i < 32; ++i) {
    __builtin_nontemporal_store(v, p);
    p += 128 * 256;  // 128 rows ahead
  }
}

extern "C" void kernel_launch(void* const* d_in, const int* in_sizes, int n_in,
                              void* d_out, int out_size, void* d_ws,
                              size_t ws_size, hipStream_t stream) {
  // setup_inputs order: query(0) key(1) value(2) Wq(3) bq(4) Wk(5) bk(6)
  //                     Wv(7) bv(8) Wo(9) bo(10)
  const float* value = (const float*)d_in[2];
  const float* Wv = (const float*)d_in[7];
  const float* bv = (const float*)d_in[8];
  const float* Wo = (const float*)d_in[9];
  const float* bo = (const float*)d_in[10];

  float* outv = (float*)d_ws;  // 8*1024 floats, 16B-aligned (harness alloc)

  k_outvec<<<B_SIZE * 16, 256, 0, stream>>>(value, (const float4*)Wv,
                                            (const float4*)bv, Wo, bo, outv);
  k_broadcast<<<B_SIZE * 128, 256, 0, stream>>>((const vfloat4*)outv,
                                                (vfloat4*)d_out);
}